// Round 13
// baseline (26.313 us; speedup 1.0000x reference)
//
#include <hip/hip_runtime.h>

#define B_ 4
#define N_ 256
#define T_ 16
#define F_ 128
#define H_ 256
#define BN_ (B_ * N_)  // 1024

// ---------------------------------------------------------------------------
// lp_prep: blocks 0..127  : hbar[bn][f] = mean_t nodefeat[bn][t][f]
//          blocks 128..143: W1T[k][h] = W1[h][k]   (LDS-tiled transpose)
// (round-3/10 version verbatim)
// ---------------------------------------------------------------------------
__global__ __launch_bounds__(1024) void lp_prep(const float* __restrict__ nf,
                                                const float* __restrict__ W1,
                                                float* __restrict__ hbar,
                                                float* __restrict__ W1T) {
    __shared__ float sT[64][65];
    const int tid = threadIdx.x;
    if (blockIdx.x < 128) {
        const int idx = blockIdx.x * 1024 + tid;   // bn*128 + f
        const int bn  = idx >> 7;
        const int f   = idx & 127;
        const float* src = nf + (size_t)bn * (T_ * F_) + f;
        float s = 0.f;
#pragma unroll
        for (int t = 0; t < T_; ++t) s += src[t * F_];
        hbar[idx] = s * (1.0f / 16.0f);
    } else {
        const int t  = blockIdx.x - 128;  // 0..15
        const int y0 = (t >> 2) * 64;     // h-tile base
        const int x0 = (t & 3) * 64;      // k-tile base
        const int ty = tid >> 6;          // 0..15
        const int tx = tid & 63;
#pragma unroll
        for (int r = 0; r < 4; ++r)
            sT[r * 16 + ty][tx] = W1[(size_t)(y0 + r * 16 + ty) * 256 + (x0 + tx)];
        __syncthreads();
#pragma unroll
        for (int r = 0; r < 4; ++r)
            W1T[(size_t)(x0 + r * 16 + ty) * 256 + (y0 + tx)] = sT[tx][r * 16 + ty];
    }
}

// ---------------------------------------------------------------------------
// lp_gemm: block = (8-node tile, h-half), 512 threads = (kq 0..3, hl 0..127).
// W1T loads lane-coalesced; hbar via wave-uniform s_load.
// Outputs: aT[tile4][h][4] (b1 folded), cT[b][h][N].
// (round-3/10 version verbatim)
// ---------------------------------------------------------------------------
__global__ __launch_bounds__(512) void lp_gemm(const float* __restrict__ hbar,
                                               const float* __restrict__ W1T,
                                               const float* __restrict__ b1,
                                               float* __restrict__ aT,
                                               float* __restrict__ cT) {
    __shared__ float red[16][4][128];  // [val][kq][hl] = 32 KB

    const int tile8 = blockIdx.x >> 1;        // 0..127 -> 8 nodes
    const int h0    = (blockIdx.x & 1) * 128; // h half
    const int bn0   = tile8 * 8;
    const int b     = bn0 >> 8;
    const int tid   = threadIdx.x;
    const int kq    = __builtin_amdgcn_readfirstlane(tid >> 7);  // 0..3
    const int hl    = tid & 127;
    const int h     = h0 + hl;

    const float* wA = W1T + (size_t)(kq * 32) * H_ + h;
    const float* wC = W1T + (size_t)(F_ + kq * 32) * H_ + h;
    const float* hb = hbar + (size_t)bn0 * F_ + kq * 32;  // wave-uniform base

    float acca[8] = {0.f, 0.f, 0.f, 0.f, 0.f, 0.f, 0.f, 0.f};
    float accc[8] = {0.f, 0.f, 0.f, 0.f, 0.f, 0.f, 0.f, 0.f};

#pragma unroll 4
    for (int kk = 0; kk < 32; ++kk) {
        const float wa = wA[(size_t)kk * H_];   // coalesced over lanes
        const float wc = wC[(size_t)kk * H_];
#pragma unroll
        for (int n = 0; n < 8; ++n) {
            const float hv = hb[n * F_ + kk];   // uniform -> s_load
            acca[n] = fmaf(hv, wa, acca[n]);
            accc[n] = fmaf(hv, wc, accc[n]);
        }
    }

#pragma unroll
    for (int n = 0; n < 8; ++n) {
        red[n][kq][hl]     = acca[n];
        red[8 + n][kq][hl] = accc[n];
    }
    __syncthreads();

    const int rv = tid >> 7;  // 0..3
#pragma unroll
    for (int i = 0; i < 4; ++i) {
        const int v = rv * 4 + i;  // 0..15
        const float s = (red[v][0][hl] + red[v][1][hl]) + (red[v][2][hl] + red[v][3][hl]);
        if (v < 8) {
            const int bn = bn0 + v;
            aT[((size_t)(bn >> 2) * H_ + h) * 4 + (bn & 3)] = s + b1[h];
        } else {
            const int n = v - 8;
            cT[((size_t)b * H_ + h) * N_ + ((bn0 & 255) + n)] = s;
        }
    }
}

// ---------------------------------------------------------------------------
// lp_k2 v7: R10's k2 (grid 512 = 4b x 32 i-tiles(8) x 4 jq(64); 1024 thr =
// (ho 0..15 -> 16-h chunk, jl 0..63); 2 blocks/CU = 32 waves/CU) with ONLY
// the inner body changed to the relu identity:
//   relu(x) = (x+|x|)/2  =>  out = 0.5*(sum|a+c|w + u_i + v_j) + b2
// |x| is a free VOP3 input modifier: 8 add + 8 abs-fma + 1 vacc-fma =
// 17 VALU/iter (was 24). Loads identical to R10 (1 cj dword + 2 uniform
// s_load_dwordx4 + W2). u_i: 8-wave shfl prologue; v_j: summed in epilogue.
// ---------------------------------------------------------------------------
__global__ __launch_bounds__(1024) void lp_k2(const float* __restrict__ aT,
                                              const float* __restrict__ cT,
                                              const float* __restrict__ W2,
                                              const float* __restrict__ b2,
                                              float* __restrict__ out) {
    __shared__ float pr[16][9][64];  // [ho][row0..7 | vacc][jl] = 36.9 KB
    __shared__ float swu[8];         // u_i per local row

    const int bx  = blockIdx.x;      // 0..511
    const int b   = bx >> 7;         // 0..3
    const int rr  = bx & 127;
    const int it  = rr >> 2;         // 0..31 : i-tile of 8 rows
    const int jq  = rr & 3;          // j quarter
    const int i0  = it * 8;
    const int j0  = jq * 64;
    const int bn0 = b * N_ + i0;     // 8-aligned

    const int tid = threadIdx.x;
    const float* a0 = aT + (size_t)(bn0 >> 2) * (H_ * 4);      // rows 0..3
    const float* a1 = a0 + H_ * 4;                             // rows 4..7

    // ---- prologue: u_r = sum_h a[r][h]*W2[h]; wave w (0..7) -> row w ----
    if (tid < 512) {
        const int wv = tid >> 6;     // 0..7 = local row
        const int l  = tid & 63;
        const float* base = (wv < 4 ? a0 : a1) + (wv & 3);
        float pa = 0.f;
#pragma unroll
        for (int e = 0; e < 4; ++e) {
            const int h = 4 * l + e;
            pa = fmaf(base[h * 4], W2[h], pa);
        }
#pragma unroll
        for (int off = 32; off >= 1; off >>= 1)
            pa += __shfl_xor(pa, off, 64);
        if (l == 0) swu[wv] = pa;
    }

    // ---- main loop (R10 structure, abs-trick body) ----
    const int ho = __builtin_amdgcn_readfirstlane(tid >> 6);  // 0..15
    const int jl = tid & 63;
    const int h0 = ho * 16;

    const float* crow = cT + (size_t)b * (H_ * N_) + j0 + jl;

    float acc0 = 0.f, acc1 = 0.f, acc2 = 0.f, acc3 = 0.f;
    float acc4 = 0.f, acc5 = 0.f, acc6 = 0.f, acc7 = 0.f;
    float vacc = 0.f;

#pragma unroll 4
    for (int hh = 0; hh < 16; ++hh) {
        const int h = h0 + hh;
        const float  cj  = crow[(size_t)h * N_];           // coalesced over jl
        const float  w   = W2[h];                          // uniform -> s_load
        const float4 av0 = *(const float4*)(a0 + h * 4);   // uniform -> s_load
        const float4 av1 = *(const float4*)(a1 + h * 4);   // uniform -> s_load
        float x;
        x = av0.x + cj; acc0 = fmaf(__builtin_fabsf(x), w, acc0);
        x = av0.y + cj; acc1 = fmaf(__builtin_fabsf(x), w, acc1);
        x = av0.z + cj; acc2 = fmaf(__builtin_fabsf(x), w, acc2);
        x = av0.w + cj; acc3 = fmaf(__builtin_fabsf(x), w, acc3);
        x = av1.x + cj; acc4 = fmaf(__builtin_fabsf(x), w, acc4);
        x = av1.y + cj; acc5 = fmaf(__builtin_fabsf(x), w, acc5);
        x = av1.z + cj; acc6 = fmaf(__builtin_fabsf(x), w, acc6);
        x = av1.w + cj; acc7 = fmaf(__builtin_fabsf(x), w, acc7);
        vacc = fmaf(cj, w, vacc);                          // v_j partial
    }

    pr[ho][0][jl] = acc0;
    pr[ho][1][jl] = acc1;
    pr[ho][2][jl] = acc2;
    pr[ho][3][jl] = acc3;
    pr[ho][4][jl] = acc4;
    pr[ho][5][jl] = acc5;
    pr[ho][6][jl] = acc6;
    pr[ho][7][jl] = acc7;
    pr[ho][8][jl] = vacc;
    __syncthreads();

    // ---- epilogue: 512 outputs (8 i x 64 j) ----
    if (tid < 512) {
        const int oi = tid >> 6;   // 0..7
        const int oj = tid & 63;
        float s = 0.f, v = 0.f;
#pragma unroll
        for (int o = 0; o < 16; ++o) {
            s += pr[o][oi][oj];
            v += pr[o][8][oj];
        }
        out[(size_t)(bn0 + oi) * N_ + j0 + oj] = 0.5f * (s + v + swu[oi]) + b2[0];
    }
}

extern "C" void kernel_launch(void* const* d_in, const int* in_sizes, int n_in,
                              void* d_out, int out_size, void* d_ws, size_t ws_size,
                              hipStream_t stream) {
    const float* nodefeat = (const float*)d_in[0];  // [B,N,T,F]
    const float* W1       = (const float*)d_in[1];  // [H, 2F]
    const float* b1       = (const float*)d_in[2];  // [H]
    const float* W2       = (const float*)d_in[3];  // [1, H]
    const float* b2       = (const float*)d_in[4];  // [1]
    float* out = (float*)d_out;                     // [B,N,N]

    float* hbar = (float*)d_ws;                     // [1024][128]        = 512 KB
    float* W1T  = hbar + (size_t)BN_ * F_;          // [256][256]         = 256 KB
    float* aT   = W1T + 256 * 256;                  // [256 tiles][H][4]  = 1 MB
    float* cT   = aT + (size_t)256 * H_ * 4;        // [B][H][N]          = 1 MB

    lp_prep<<<144, 1024, 0, stream>>>(nodefeat, W1, hbar, W1T);
    lp_gemm<<<256, 512, 0, stream>>>(hbar, W1T, b1, aT, cT);
    lp_k2<<<512, 1024, 0, stream>>>(aT, cT, W2, b2, out);
}

// Round 14
// 24.767 us; speedup vs baseline: 1.0624x; 1.0624x over previous
//
#include <hip/hip_runtime.h>

#define B_ 4
#define N_ 256
#define T_ 16
#define F_ 128
#define H_ 256
#define BN_ (B_ * N_)  // 1024

// ---------------------------------------------------------------------------
// lp_prep: blocks 0..127  : hbar[bn][f] = mean_t nodefeat[bn][t][f]
//          blocks 128..143: W1T[k][h] = W1[h][k]   (LDS-tiled transpose)
// (round-3/10 version verbatim)
// ---------------------------------------------------------------------------
__global__ __launch_bounds__(1024) void lp_prep(const float* __restrict__ nf,
                                                const float* __restrict__ W1,
                                                float* __restrict__ hbar,
                                                float* __restrict__ W1T) {
    __shared__ float sT[64][65];
    const int tid = threadIdx.x;
    if (blockIdx.x < 128) {
        const int idx = blockIdx.x * 1024 + tid;   // bn*128 + f
        const int bn  = idx >> 7;
        const int f   = idx & 127;
        const float* src = nf + (size_t)bn * (T_ * F_) + f;
        float s = 0.f;
#pragma unroll
        for (int t = 0; t < T_; ++t) s += src[t * F_];
        hbar[idx] = s * (1.0f / 16.0f);
    } else {
        const int t  = blockIdx.x - 128;  // 0..15
        const int y0 = (t >> 2) * 64;     // h-tile base
        const int x0 = (t & 3) * 64;      // k-tile base
        const int ty = tid >> 6;          // 0..15
        const int tx = tid & 63;
#pragma unroll
        for (int r = 0; r < 4; ++r)
            sT[r * 16 + ty][tx] = W1[(size_t)(y0 + r * 16 + ty) * 256 + (x0 + tx)];
        __syncthreads();
#pragma unroll
        for (int r = 0; r < 4; ++r)
            W1T[(size_t)(x0 + r * 16 + ty) * 256 + (y0 + tx)] = sT[tx][r * 16 + ty];
    }
}

// ---------------------------------------------------------------------------
// lp_gemm: block = (8-node tile, h-half), 512 threads = (kq 0..3, hl 0..127).
// W1T loads lane-coalesced; hbar via wave-uniform s_load.
// Outputs: aT[tile4][h][4] (b1 folded), cT[b][h][N].
// (round-3/10 version verbatim)
// ---------------------------------------------------------------------------
__global__ __launch_bounds__(512) void lp_gemm(const float* __restrict__ hbar,
                                               const float* __restrict__ W1T,
                                               const float* __restrict__ b1,
                                               float* __restrict__ aT,
                                               float* __restrict__ cT) {
    __shared__ float red[16][4][128];  // [val][kq][hl] = 32 KB

    const int tile8 = blockIdx.x >> 1;        // 0..127 -> 8 nodes
    const int h0    = (blockIdx.x & 1) * 128; // h half
    const int bn0   = tile8 * 8;
    const int b     = bn0 >> 8;
    const int tid   = threadIdx.x;
    const int kq    = __builtin_amdgcn_readfirstlane(tid >> 7);  // 0..3
    const int hl    = tid & 127;
    const int h     = h0 + hl;

    const float* wA = W1T + (size_t)(kq * 32) * H_ + h;
    const float* wC = W1T + (size_t)(F_ + kq * 32) * H_ + h;
    const float* hb = hbar + (size_t)bn0 * F_ + kq * 32;  // wave-uniform base

    float acca[8] = {0.f, 0.f, 0.f, 0.f, 0.f, 0.f, 0.f, 0.f};
    float accc[8] = {0.f, 0.f, 0.f, 0.f, 0.f, 0.f, 0.f, 0.f};

#pragma unroll 4
    for (int kk = 0; kk < 32; ++kk) {
        const float wa = wA[(size_t)kk * H_];   // coalesced over lanes
        const float wc = wC[(size_t)kk * H_];
#pragma unroll
        for (int n = 0; n < 8; ++n) {
            const float hv = hb[n * F_ + kk];   // uniform -> s_load
            acca[n] = fmaf(hv, wa, acca[n]);
            accc[n] = fmaf(hv, wc, accc[n]);
        }
    }

#pragma unroll
    for (int n = 0; n < 8; ++n) {
        red[n][kq][hl]     = acca[n];
        red[8 + n][kq][hl] = accc[n];
    }
    __syncthreads();

    const int rv = tid >> 7;  // 0..3
#pragma unroll
    for (int i = 0; i < 4; ++i) {
        const int v = rv * 4 + i;  // 0..15
        const float s = (red[v][0][hl] + red[v][1][hl]) + (red[v][2][hl] + red[v][3][hl]);
        if (v < 8) {
            const int bn = bn0 + v;
            aT[((size_t)(bn >> 2) * H_ + h) * 4 + (bn & 3)] = s + b1[h];
        } else {
            const int n = v - 8;
            cT[((size_t)b * H_ + h) * N_ + ((bn0 & 255) + n)] = s;
        }
    }
}

// ---------------------------------------------------------------------------
// lp_k2 v8: R10's k2 verbatim EXCEPT the 16 cj loads are prefetched into a
// fully-unrolled register array before the FMA chain (MLP 4 -> 16 outstanding
// loads/wave; +16 VGPR, no occupancy change).
// Grid 512 = 4 b x 32 i-tiles(8 rows) x 4 j-quarters(64 j).
// 1024 threads = (ho 0..15 = 16-wide h-chunk, jl 0..63); 2 blocks/CU.
// ---------------------------------------------------------------------------
__global__ __launch_bounds__(1024) void lp_k2(const float* __restrict__ aT,
                                              const float* __restrict__ cT,
                                              const float* __restrict__ W2,
                                              const float* __restrict__ b2,
                                              float* __restrict__ out) {
    __shared__ float pr[16][8][64];  // [ho][i][jl] = 32 KB

    const int bx  = blockIdx.x;      // 0..511
    const int b   = bx >> 7;         // 0..3
    const int rr  = bx & 127;
    const int it  = rr >> 2;         // 0..31 : i-tile of 8 rows
    const int jq  = rr & 3;          // j quarter
    const int i0  = it * 8;
    const int j0  = jq * 64;
    const int bn0 = b * N_ + i0;

    const int tid = threadIdx.x;
    const int ho  = __builtin_amdgcn_readfirstlane(tid >> 6);  // 0..15, wave-uniform
    const int jl  = tid & 63;

    const float* crow = cT + (size_t)b * (H_ * N_) + j0 + jl;
    const float* a0 = aT + (size_t)(bn0 >> 2) * (H_ * 4);      // uniform base
    const float* a1 = a0 + H_ * 4;
    const int h0 = ho * 16;

    // ---- prefetch: all 16 cj dwords in flight (static indices -> VGPRs) ----
    float cjv[16];
#pragma unroll
    for (int hh = 0; hh < 16; ++hh)
        cjv[hh] = crow[(size_t)(h0 + hh) * N_];   // coalesced over jl

    float acc0 = 0.f, acc1 = 0.f, acc2 = 0.f, acc3 = 0.f;
    float acc4 = 0.f, acc5 = 0.f, acc6 = 0.f, acc7 = 0.f;

#pragma unroll
    for (int hh = 0; hh < 16; ++hh) {
        const int h = h0 + hh;
        const float  cj  = cjv[hh];
        const float  w   = W2[h];                          // uniform -> s_load
        const float4 av0 = *(const float4*)(a0 + h * 4);   // uniform -> s_load
        const float4 av1 = *(const float4*)(a1 + h * 4);   // uniform -> s_load
        float x;
        x = av0.x + cj; acc0 = fmaf(fmaxf(x, 0.f), w, acc0);
        x = av0.y + cj; acc1 = fmaf(fmaxf(x, 0.f), w, acc1);
        x = av0.z + cj; acc2 = fmaf(fmaxf(x, 0.f), w, acc2);
        x = av0.w + cj; acc3 = fmaf(fmaxf(x, 0.f), w, acc3);
        x = av1.x + cj; acc4 = fmaf(fmaxf(x, 0.f), w, acc4);
        x = av1.y + cj; acc5 = fmaf(fmaxf(x, 0.f), w, acc5);
        x = av1.z + cj; acc6 = fmaf(fmaxf(x, 0.f), w, acc6);
        x = av1.w + cj; acc7 = fmaf(fmaxf(x, 0.f), w, acc7);
    }

    pr[ho][0][jl] = acc0;
    pr[ho][1][jl] = acc1;
    pr[ho][2][jl] = acc2;
    pr[ho][3][jl] = acc3;
    pr[ho][4][jl] = acc4;
    pr[ho][5][jl] = acc5;
    pr[ho][6][jl] = acc6;
    pr[ho][7][jl] = acc7;
    __syncthreads();

    // combine: 512 outputs (8 i x 64 j); 16 LDS reads each (2-way bank = free)
    if (tid < 512) {
        const int oi = tid >> 6;   // 0..7
        const int oj = tid & 63;
        float s = 0.f;
#pragma unroll
        for (int o = 0; o < 16; ++o) s += pr[o][oi][oj];
        out[(size_t)(bn0 + oi) * N_ + j0 + oj] = s + b2[0];
    }
}

extern "C" void kernel_launch(void* const* d_in, const int* in_sizes, int n_in,
                              void* d_out, int out_size, void* d_ws, size_t ws_size,
                              hipStream_t stream) {
    const float* nodefeat = (const float*)d_in[0];  // [B,N,T,F]
    const float* W1       = (const float*)d_in[1];  // [H, 2F]
    const float* b1       = (const float*)d_in[2];  // [H]
    const float* W2       = (const float*)d_in[3];  // [1, H]
    const float* b2       = (const float*)d_in[4];  // [1]
    float* out = (float*)d_out;                     // [B,N,N]

    float* hbar = (float*)d_ws;                     // [1024][128]        = 512 KB
    float* W1T  = hbar + (size_t)BN_ * F_;          // [256][256]         = 256 KB
    float* aT   = W1T + 256 * 256;                  // [256 tiles][H][4]  = 1 MB
    float* cT   = aT + (size_t)256 * H_ * 4;        // [B][H][N]          = 1 MB

    lp_prep<<<144, 1024, 0, stream>>>(nodefeat, W1, hbar, W1T);
    lp_gemm<<<256, 512, 0, stream>>>(hbar, W1T, b1, aT, cT);
    lp_k2<<<512, 1024, 0, stream>>>(aT, cT, W2, b2, out);
}

// Round 15
// 24.009 us; speedup vs baseline: 1.0960x; 1.0316x over previous
//
#include <hip/hip_runtime.h>

#define B_ 4
#define N_ 256
#define T_ 16
#define F_ 128
#define H_ 256
#define BN_ (B_ * N_)  // 1024

// ---------------------------------------------------------------------------
// FINAL (= round-10 best config, 24.23 us).
// Accounting: ~17.5 us fixed harness/graph overhead + prep 1.4 (HBM floor
// 1.3) + gemm 1.1 (VALU floor 0.9) + k2 4.2 (VALU floor 2.6, rest is
// distributed issue/tail overhead — all single-variable levers tested:
// occupancy 2x WIN; traffic/2, prefetch, abs-trick, wide-j all neutral/worse).
// ---------------------------------------------------------------------------

// lp_prep: blocks 0..127  : hbar[bn][f] = mean_t nodefeat[bn][t][f]
//          blocks 128..143: W1T[k][h] = W1[h][k]   (LDS-tiled transpose)
__global__ __launch_bounds__(1024) void lp_prep(const float* __restrict__ nf,
                                                const float* __restrict__ W1,
                                                float* __restrict__ hbar,
                                                float* __restrict__ W1T) {
    __shared__ float sT[64][65];
    const int tid = threadIdx.x;
    if (blockIdx.x < 128) {
        const int idx = blockIdx.x * 1024 + tid;   // bn*128 + f
        const int bn  = idx >> 7;
        const int f   = idx & 127;
        const float* src = nf + (size_t)bn * (T_ * F_) + f;
        float s = 0.f;
#pragma unroll
        for (int t = 0; t < T_; ++t) s += src[t * F_];
        hbar[idx] = s * (1.0f / 16.0f);
    } else {
        const int t  = blockIdx.x - 128;  // 0..15
        const int y0 = (t >> 2) * 64;     // h-tile base
        const int x0 = (t & 3) * 64;      // k-tile base
        const int ty = tid >> 6;          // 0..15
        const int tx = tid & 63;
#pragma unroll
        for (int r = 0; r < 4; ++r)
            sT[r * 16 + ty][tx] = W1[(size_t)(y0 + r * 16 + ty) * 256 + (x0 + tx)];
        __syncthreads();
#pragma unroll
        for (int r = 0; r < 4; ++r)
            W1T[(size_t)(x0 + r * 16 + ty) * 256 + (y0 + tx)] = sT[tx][r * 16 + ty];
    }
}

// lp_gemm: block = (8-node tile, h-half), 512 threads = (kq 0..3, hl 0..127).
// W1T loads lane-coalesced; hbar via wave-uniform s_load.
// Outputs: aT[tile4][h][4] (b1 folded), cT[b][h][N].
__global__ __launch_bounds__(512) void lp_gemm(const float* __restrict__ hbar,
                                               const float* __restrict__ W1T,
                                               const float* __restrict__ b1,
                                               float* __restrict__ aT,
                                               float* __restrict__ cT) {
    __shared__ float red[16][4][128];  // [val][kq][hl] = 32 KB

    const int tile8 = blockIdx.x >> 1;        // 0..127 -> 8 nodes
    const int h0    = (blockIdx.x & 1) * 128; // h half
    const int bn0   = tile8 * 8;
    const int b     = bn0 >> 8;
    const int tid   = threadIdx.x;
    const int kq    = __builtin_amdgcn_readfirstlane(tid >> 7);  // 0..3
    const int hl    = tid & 127;
    const int h     = h0 + hl;

    const float* wA = W1T + (size_t)(kq * 32) * H_ + h;
    const float* wC = W1T + (size_t)(F_ + kq * 32) * H_ + h;
    const float* hb = hbar + (size_t)bn0 * F_ + kq * 32;  // wave-uniform base

    float acca[8] = {0.f, 0.f, 0.f, 0.f, 0.f, 0.f, 0.f, 0.f};
    float accc[8] = {0.f, 0.f, 0.f, 0.f, 0.f, 0.f, 0.f, 0.f};

#pragma unroll 4
    for (int kk = 0; kk < 32; ++kk) {
        const float wa = wA[(size_t)kk * H_];   // coalesced over lanes
        const float wc = wC[(size_t)kk * H_];
#pragma unroll
        for (int n = 0; n < 8; ++n) {
            const float hv = hb[n * F_ + kk];   // uniform -> s_load
            acca[n] = fmaf(hv, wa, acca[n]);
            accc[n] = fmaf(hv, wc, accc[n]);
        }
    }

#pragma unroll
    for (int n = 0; n < 8; ++n) {
        red[n][kq][hl]     = acca[n];
        red[8 + n][kq][hl] = accc[n];
    }
    __syncthreads();

    const int rv = tid >> 7;  // 0..3
#pragma unroll
    for (int i = 0; i < 4; ++i) {
        const int v = rv * 4 + i;  // 0..15
        const float s = (red[v][0][hl] + red[v][1][hl]) + (red[v][2][hl] + red[v][3][hl]);
        if (v < 8) {
            const int bn = bn0 + v;
            aT[((size_t)(bn >> 2) * H_ + h) * 4 + (bn & 3)] = s + b1[h];
        } else {
            const int n = v - 8;
            cT[((size_t)b * H_ + h) * N_ + ((bn0 & 255) + n)] = s;
        }
    }
}

// lp_k2 (round-10 best): 2 blocks/CU (32 waves/CU) for latency hiding.
// Grid 512 = 4 b x 32 i-tiles(8 rows) x 4 j-quarters(64 j).
// 1024 threads = (ho in 0..15 = 16-wide h-chunk, jl in 0..63).
// Per h-iter: 1 coalesced cT dword + 2 uniform s_load_dwordx4 a-pairs +
// 1 uniform W2 + 24 VALU. LDS pr[16][8][64] = 32 KB -> 2 blocks/CU.
__global__ __launch_bounds__(1024) void lp_k2(const float* __restrict__ aT,
                                              const float* __restrict__ cT,
                                              const float* __restrict__ W2,
                                              const float* __restrict__ b2,
                                              float* __restrict__ out) {
    __shared__ float pr[16][8][64];  // [ho][i][jl] = 32 KB

    const int bx  = blockIdx.x;      // 0..511
    const int b   = bx >> 7;         // 0..3
    const int rr  = bx & 127;
    const int it  = rr >> 2;         // 0..31 : i-tile of 8 rows
    const int jq  = rr & 3;          // j quarter
    const int i0  = it * 8;
    const int j0  = jq * 64;
    const int bn0 = b * N_ + i0;

    const int tid = threadIdx.x;
    const int ho  = __builtin_amdgcn_readfirstlane(tid >> 6);  // 0..15, wave-uniform
    const int jl  = tid & 63;

    const float* crow = cT + (size_t)b * (H_ * N_) + j0 + jl;
    const float* a0 = aT + (size_t)(bn0 >> 2) * (H_ * 4);      // uniform base
    const float* a1 = a0 + H_ * 4;
    const int h0 = ho * 16;

    float acc0 = 0.f, acc1 = 0.f, acc2 = 0.f, acc3 = 0.f;
    float acc4 = 0.f, acc5 = 0.f, acc6 = 0.f, acc7 = 0.f;

#pragma unroll 4
    for (int hh = 0; hh < 16; ++hh) {
        const int h = h0 + hh;
        const float  cj  = crow[(size_t)h * N_];           // coalesced over jl
        const float  w   = W2[h];                          // uniform -> s_load
        const float4 av0 = *(const float4*)(a0 + h * 4);   // uniform -> s_load
        const float4 av1 = *(const float4*)(a1 + h * 4);   // uniform -> s_load
        float x;
        x = av0.x + cj; acc0 = fmaf(fmaxf(x, 0.f), w, acc0);
        x = av0.y + cj; acc1 = fmaf(fmaxf(x, 0.f), w, acc1);
        x = av0.z + cj; acc2 = fmaf(fmaxf(x, 0.f), w, acc2);
        x = av0.w + cj; acc3 = fmaf(fmaxf(x, 0.f), w, acc3);
        x = av1.x + cj; acc4 = fmaf(fmaxf(x, 0.f), w, acc4);
        x = av1.y + cj; acc5 = fmaf(fmaxf(x, 0.f), w, acc5);
        x = av1.z + cj; acc6 = fmaf(fmaxf(x, 0.f), w, acc6);
        x = av1.w + cj; acc7 = fmaf(fmaxf(x, 0.f), w, acc7);
    }

    pr[ho][0][jl] = acc0;
    pr[ho][1][jl] = acc1;
    pr[ho][2][jl] = acc2;
    pr[ho][3][jl] = acc3;
    pr[ho][4][jl] = acc4;
    pr[ho][5][jl] = acc5;
    pr[ho][6][jl] = acc6;
    pr[ho][7][jl] = acc7;
    __syncthreads();

    // combine: 512 outputs (8 i x 64 j); 16 LDS reads each (2-way bank = free)
    if (tid < 512) {
        const int oi = tid >> 6;   // 0..7
        const int oj = tid & 63;
        float s = 0.f;
#pragma unroll
        for (int o = 0; o < 16; ++o) s += pr[o][oi][oj];
        out[(size_t)(bn0 + oi) * N_ + j0 + oj] = s + b2[0];
    }
}

extern "C" void kernel_launch(void* const* d_in, const int* in_sizes, int n_in,
                              void* d_out, int out_size, void* d_ws, size_t ws_size,
                              hipStream_t stream) {
    const float* nodefeat = (const float*)d_in[0];  // [B,N,T,F]
    const float* W1       = (const float*)d_in[1];  // [H, 2F]
    const float* b1       = (const float*)d_in[2];  // [H]
    const float* W2       = (const float*)d_in[3];  // [1, H]
    const float* b2       = (const float*)d_in[4];  // [1]
    float* out = (float*)d_out;                     // [B,N,N]

    float* hbar = (float*)d_ws;                     // [1024][128]        = 512 KB
    float* W1T  = hbar + (size_t)BN_ * F_;          // [256][256]         = 256 KB
    float* aT   = W1T + 256 * 256;                  // [256 tiles][H][4]  = 1 MB
    float* cT   = aT + (size_t)256 * H_ * 4;        // [B][H][N]          = 1 MB

    lp_prep<<<144, 1024, 0, stream>>>(nodefeat, W1, hbar, W1T);
    lp_gemm<<<256, 512, 0, stream>>>(hbar, W1T, b1, aT, cT);
    lp_k2<<<512, 1024, 0, stream>>>(aT, cT, W2, b2, out);
}